// Round 3
// baseline (354.411 us; speedup 1.0000x reference)
//
#include <hip/hip_runtime.h>

#define FDIM 64

typedef unsigned short u16;
typedef unsigned int u32;
typedef float v2f __attribute__((ext_vector_type(2)));

// pack 4 f32 -> 4 fp8 e4m3 (OCP on gfx950) in one u32
__device__ __forceinline__ u32 pk_fp8x4(float a, float b, float c, float d) {
    u32 p = __builtin_amdgcn_cvt_pk_fp8_f32(a, b, 0, false);
    p = __builtin_amdgcn_cvt_pk_fp8_f32(c, d, p, true);
    return p;
}

// ========= mm compute phase: t[64 rows] = As @ Ws (fp8 out) =========
// Known-good structure: As f32 in LDS (64x65), Ws f32 in LDS.
// SCALE: multiply output row R by rsqrt(cnt[R]+1) before fp8 pack (folds
// the source-side GCN norm into t; consumer aggregate needs no per-edge
// dinv gather).

template <bool SCALE>
__device__ __forceinline__ void mm_compute(
    u32* __restrict__ t, const int* __restrict__ cnt, int n, int r0,
    float (*__restrict__ As)[FDIM + 1], const float* __restrict__ Ws)
{
    int tid = threadIdx.x;
    int rq = tid >> 4;   // rows rq*4..+3
    int cq = tid & 15;   // cols cq*4..+3
    float acc[4][4];
    #pragma unroll
    for (int i = 0; i < 4; ++i)
        #pragma unroll
        for (int j = 0; j < 4; ++j) acc[i][j] = 0.f;

    const float4* Ws4 = (const float4*)Ws;
    #pragma unroll 4
    for (int k = 0; k < FDIM; ++k) {
        float4 w = Ws4[k * 16 + cq];
        float a[4];
        #pragma unroll
        for (int i = 0; i < 4; ++i) a[i] = As[rq * 4 + i][k];
        #pragma unroll
        for (int i = 0; i < 4; ++i) {
            acc[i][0] = fmaf(a[i], w.x, acc[i][0]);
            acc[i][1] = fmaf(a[i], w.y, acc[i][1]);
            acc[i][2] = fmaf(a[i], w.z, acc[i][2]);
            acc[i][3] = fmaf(a[i], w.w, acc[i][3]);
        }
    }

    #pragma unroll
    for (int i = 0; i < 4; ++i) {
        int R = r0 + rq * 4 + i;
        if (R < n) {
            float sc = 1.0f;
            if (SCALE) sc = rsqrtf((float)cnt[R] + 1.0f);
            t[(size_t)R * 16 + cq] =
                pk_fp8x4(acc[i][0] * sc, acc[i][1] * sc,
                         acc[i][2] * sc, acc[i][3] * sc);
        }
    }
}

// ===== combined dispatch: CSR-fill blocks (first) + matmul1 blocks =========
// Fill: partitioned grid-stride, 8 independent atomic chains in flight.
// (Proven config: insensitive to wave count / depth / counter padding ->
// throughput-bound at the coherence point; keep the cheapest version.)

__global__ __launch_bounds__(256) void k_mm_fill(
    const float* __restrict__ x, const float* __restrict__ W1,
    u32* __restrict__ t,
    const int* __restrict__ src, const int* __restrict__ dst,
    int* __restrict__ cnt, int* __restrict__ csr,
    int n, int E, int cap, int fill_blocks)
{
    __shared__ float As[64][FDIM + 1];
    __shared__ float Ws[FDIM * FDIM];

    if ((int)blockIdx.x < fill_blocks) {
        int stride = fill_blocks * 256;
        int e = blockIdx.x * 256 + threadIdx.x;
        for (; e + 7 * stride < E; e += 8 * stride) {
            int d[8], s[8], p[8];
            #pragma unroll
            for (int u = 0; u < 8; ++u)
                d[u] = __builtin_nontemporal_load(&dst[e + u * stride]);
            #pragma unroll
            for (int u = 0; u < 8; ++u)
                s[u] = __builtin_nontemporal_load(&src[e + u * stride]);
            #pragma unroll
            for (int u = 0; u < 8; ++u) p[u] = atomicAdd(&cnt[d[u]], 1);
            #pragma unroll
            for (int u = 0; u < 8; ++u)
                if (p[u] < cap) csr[(size_t)d[u] * cap + p[u]] = s[u];
        }
        for (; e < E; e += stride) {
            int d = dst[e];
            int p = atomicAdd(&cnt[d], 1);
            if (p < cap) csr[(size_t)d * cap + p] = src[e];
        }
        return;
    }

    int blk = blockIdx.x - fill_blocks;
    int r0 = blk * 64;
    int tid = threadIdx.x;
    #pragma unroll
    for (int i = 0; i < 4; ++i)
        ((float4*)Ws)[tid + 256 * i] = ((const float4*)W1)[tid + 256 * i];

    // stage x rows (f32, no bias, no relu)
    #pragma unroll
    for (int i = 0; i < 4; ++i) {
        int idx = tid + 256 * i;
        int r = idx >> 4;
        int kq = idx & 15;
        float4 v = make_float4(0.f, 0.f, 0.f, 0.f);
        int R = r0 + r;
        if (R < n) v = ((const float4*)x)[(size_t)R * 16 + kq];
        As[r][kq * 4 + 0] = v.x;
        As[r][kq * 4 + 1] = v.y;
        As[r][kq * 4 + 2] = v.z;
        As[r][kq * 4 + 3] = v.w;
    }
    __syncthreads();
    mm_compute<false>(t, nullptr, n, r0, As, Ws);
}

// ======= gather-aggregate body for one node (16-lane group) ================
// SCALED=true: t rows already carry dinv_j -> just sum gathers.
// SCALED=false (layer 1, t produced before cnt final): gather cnt[sv],
// rsqrt in chain (measured-free in rounds 1/2).
// Gathers predicated on u<cm (uniform per group): invalid slots issue no
// load at all (saves ~30% of gather line-ops at avg deg 10).

template <bool SCALED>
__device__ __forceinline__ float4 agg_node(
    int i, const int* __restrict__ cnt, const int* __restrict__ csr,
    const u32* __restrict__ t, int cap, int li, int nbase)
{
    int dg = cnt[i];
    float di = rsqrtf((float)dg + 1.0f);
    int m = dg < cap ? dg : cap;

    u32 sp = t[(size_t)i * 16 + li];
    v2f s0 = __builtin_amdgcn_cvt_pk_f32_fp8(sp, false);
    v2f s1 = __builtin_amdgcn_cvt_pk_f32_fp8(sp, true);
    float4 A0, A1, A2, A3;
    if (SCALED) {
        A0 = make_float4(s0.x, s0.y, s1.x, s1.y);
    } else {
        A0 = make_float4(s0.x * di, s0.y * di, s1.x * di, s1.y * di);
    }
    A1 = make_float4(0.f, 0.f, 0.f, 0.f);
    A2 = make_float4(0.f, 0.f, 0.f, 0.f);
    A3 = make_float4(0.f, 0.f, 0.f, 0.f);

    const int* row = csr + (size_t)i * cap;

    for (int c0 = 0; c0 < m; c0 += 16) {
        int cm = m - c0; if (cm > 16) cm = 16;
        int sv = 0; float dvv = 0.f;
        if (li < cm) {
            sv = __builtin_nontemporal_load(&row[c0 + li]);
            if (!SCALED) dvv = rsqrtf((float)cnt[sv] + 1.0f);
        }
        int jv[16]; float dj[16]; u32 v[16];
        #pragma unroll
        for (int u = 0; u < 16; ++u) {
            jv[u] = __shfl(sv, nbase + u);
            if (!SCALED) dj[u] = __shfl(dvv, nbase + u);
        }
        #pragma unroll
        for (int u = 0; u < 16; ++u) {
            v[u] = 0;
            if (u < cm) v[u] = t[(size_t)jv[u] * 16 + li];
        }
        #pragma unroll
        for (int u = 0; u < 16; ++u) {
            v2f x0 = __builtin_amdgcn_cvt_pk_f32_fp8(v[u], false);
            v2f x1 = __builtin_amdgcn_cvt_pk_f32_fp8(v[u], true);
            float4* Ap = (u & 3) == 0 ? &A0 : (u & 3) == 1 ? &A1 :
                         (u & 3) == 2 ? &A2 : &A3;
            if (SCALED) {
                Ap->x += x0.x; Ap->y += x0.y;
                Ap->z += x1.x; Ap->w += x1.y;
            } else {
                Ap->x = fmaf(x0.x, dj[u], Ap->x);
                Ap->y = fmaf(x0.y, dj[u], Ap->y);
                Ap->z = fmaf(x1.x, dj[u], Ap->z);
                Ap->w = fmaf(x1.y, dj[u], Ap->w);
            }
        }
    }

    float4 O;
    O.x = ((A0.x + A1.x) + (A2.x + A3.x)) * di;
    O.y = ((A0.y + A1.y) + (A2.y + A3.y)) * di;
    O.z = ((A0.z + A1.z) + (A2.z + A3.z)) * di;
    O.w = ((A0.w + A1.w) + (A2.w + A3.w)) * di;
    return O;
}

// == fused aggregate + matmul: block aggregates 64 nodes into As (f32 LDS,
// no bf16 round-trip), then runs the mm compute phase. Output pre-scaled
// by dinv. Replaces k_aggregate + k_matmul_h (2 dispatches -> 1, and kills
// the 12.8MB agg intermediate).

template <bool SCALED_IN>
__global__ __launch_bounds__(256) void k_aggmm(
    const int* __restrict__ cnt, const int* __restrict__ csr,
    const u32* __restrict__ tin, const float* __restrict__ Wm,
    const float* __restrict__ bias, u32* __restrict__ tout,
    int n, int cap)
{
    __shared__ float As[64][FDIM + 1];
    __shared__ float Ws[FDIM * FDIM];
    int tid = threadIdx.x;
    #pragma unroll
    for (int i = 0; i < 4; ++i)
        ((float4*)Ws)[tid + 256 * i] = ((const float4*)Wm)[tid + 256 * i];

    int r0 = blockIdx.x * 64;
    int group = tid >> 4;          // 0..15
    int li = tid & 15;
    int nbase = ((tid & 63) >> 4) << 4;
    float4 b = ((const float4*)bias)[li];

    #pragma unroll 1
    for (int r = 0; r < 4; ++r) {
        int row = r * 16 + group;
        int i = r0 + row;
        float4 v = make_float4(0.f, 0.f, 0.f, 0.f);
        if (i < n) {
            float4 O = agg_node<SCALED_IN>(i, cnt, csr, tin, cap, li, nbase);
            v.x = fmaxf(O.x + b.x, 0.f);
            v.y = fmaxf(O.y + b.y, 0.f);
            v.z = fmaxf(O.z + b.z, 0.f);
            v.w = fmaxf(O.w + b.w, 0.f);
        }
        As[row][li * 4 + 0] = v.x;
        As[row][li * 4 + 1] = v.y;
        As[row][li * 4 + 2] = v.z;
        As[row][li * 4 + 3] = v.w;
    }
    __syncthreads();
    mm_compute<true>(tout, cnt, n, r0, As, Ws);
}

// == layer-3 aggregate fused with pool AND the final reduce+linear: the
// last block per graph (atomic ticket) sums the partials and applies
// b3 + Wlin + blin. Replaces k_agg_pool + k_pool2.

__global__ __launch_bounds__(256) void k_agg_pool(
    const int* __restrict__ cnt, const int* __restrict__ csr,
    const u32* __restrict__ t, const int* __restrict__ batch,
    float* __restrict__ partial, int* __restrict__ done,
    const float* __restrict__ b3, const float* __restrict__ Wlin,
    const float* __restrict__ blin, float* __restrict__ out,
    int n, int cap, int npart, int fout)
{
    int g = blockIdx.x / npart;
    int part = blockIdx.x - g * npart;
    int tid = threadIdx.x;

    int lo = 0, hi = n;
    while (lo < hi) { int mid = (lo + hi) >> 1; if (batch[mid] < g) lo = mid + 1; else hi = mid; }
    int start = lo;
    hi = n;
    while (lo < hi) { int mid = (lo + hi) >> 1; if (batch[mid] <= g) lo = mid + 1; else hi = mid; }
    int end = lo;

    int group = tid >> 4;     // 0..15
    int li = tid & 15;
    int nbase = ((tid & 63) >> 4) << 4;

    float4 acc = make_float4(0.f, 0.f, 0.f, 0.f);
    for (int i = start + part * 16 + group; i < end; i += npart * 16) {
        float4 O = agg_node<true>(i, cnt, csr, t, cap, li, nbase);
        acc.x += O.x; acc.y += O.y; acc.z += O.z; acc.w += O.w;
    }

    __shared__ float4 red[16][16];
    red[group][li] = acc;
    __syncthreads();
    if (tid < 16) {
        float4 s = make_float4(0.f, 0.f, 0.f, 0.f);
        #pragma unroll
        for (int q = 0; q < 16; ++q) {
            s.x += red[q][tid].x; s.y += red[q][tid].y;
            s.z += red[q][tid].z; s.w += red[q][tid].w;
        }
        ((float4*)partial)[((size_t)g * npart + part) * 16 + tid] = s;
    }

    // ---- last block per graph reduces + final linear ----
    __threadfence();
    __syncthreads();
    __shared__ int lastflag;
    if (tid == 0) {
        int old = atomicAdd(&done[g], 1);
        lastflag = (old == npart - 1);
    }
    __syncthreads();
    if (!lastflag) return;
    __threadfence();   // acquire: other blocks' partials now visible

    int cg = end - start;
    __shared__ float pooled[64];
    if (tid < 64) {
        float v = 0.f;
        for (int p = 0; p < npart; ++p)
            v += partial[((size_t)g * npart + p) * 64 + tid];
        pooled[tid] = (cg > 0) ? (v / (float)cg + b3[tid]) : 0.f;
    }
    __syncthreads();
    if (tid < fout) {
        float o = blin[tid];
        for (int k = 0; k < 64; ++k) o += pooled[k] * Wlin[k * fout + tid];
        out[(size_t)g * fout + tid] = o;
    }
}

// ================= launcher =================

extern "C" void kernel_launch(void* const* d_in, const int* in_sizes, int n_in,
                              void* d_out, int out_size, void* d_ws, size_t ws_size,
                              hipStream_t stream) {
    const float* x     = (const float*)d_in[0];
    const int*   ei    = (const int*)d_in[1];
    const int*   batch = (const int*)d_in[2];
    const float* W1 = (const float*)d_in[3];
    const float* b1 = (const float*)d_in[4];
    const float* W2 = (const float*)d_in[5];
    const float* b2 = (const float*)d_in[6];
    const float* W3 = (const float*)d_in[7];
    const float* b3 = (const float*)d_in[8];
    const float* Wl = (const float*)d_in[9];
    const float* bl = (const float*)d_in[10];

    int n = in_sizes[0] / 64;
    int E = in_sizes[1] / 2;
    int fout = in_sizes[10];
    int ngraphs = out_size / fout;

    const int* srcp = ei;
    const int* dstp = ei + E;

    const int npart = 16;

    // ws layout: tA fp8 | tB fp8 | cnt | done | partial | csr
    // (cnt+done contiguous -> one memset)
    u32* tA = (u32*)d_ws;                            // n*16 u32
    u32* tB = tA + (size_t)n * 16;                   // n*16 u32
    int* cnt = (int*)(tB + (size_t)n * 16);          // n
    int* done = cnt + n;                             // ngraphs
    float* partial = (float*)(done + ngraphs);       // ngraphs*npart*64
    int* csr = (int*)(partial + (size_t)ngraphs * npart * 64);

    size_t fixed = (size_t)n * 16 * 4 * 2 + (size_t)n * 4 + (size_t)ngraphs * 4 +
                   (size_t)ngraphs * npart * 64 * 4;
    int cap = 64;
    while (cap > 32 && fixed + (size_t)n * cap * 4 > ws_size) cap -= 8;

    int mm_blocks = (n + 63) / 64;
    int fill_blocks = 256;

    // one memset: cnt + done
    hipMemsetAsync(cnt, 0, (size_t)(n + ngraphs) * sizeof(int), stream);
    // CSR build + t1 = x @ W1 (fp8, unscaled), one dispatch
    k_mm_fill<<<fill_blocks + mm_blocks, 256, 0, stream>>>(
        x, W1, tA, srcp, dstp, cnt, csr, n, E, cap, fill_blocks);

    // layer1 agg (unscaled t1) + layer2 matmul -> t2 (pre-scaled)
    k_aggmm<false><<<mm_blocks, 256, 0, stream>>>(cnt, csr, tA, W2, b1, tB, n, cap);
    // layer2 agg (scaled t2) + layer3 matmul -> t3 (pre-scaled)
    k_aggmm<true><<<mm_blocks, 256, 0, stream>>>(cnt, csr, tB, W3, b2, tA, n, cap);
    // layer3 agg + pool + final linear (last-block reduce)
    k_agg_pool<<<ngraphs * npart, 256, 0, stream>>>(
        cnt, csr, tA, batch, partial, done, b3, Wl, bl,
        (float*)d_out, n, cap, npart, fout);
}

// Round 4
// 340.815 us; speedup vs baseline: 1.0399x; 1.0399x over previous
//
#include <hip/hip_runtime.h>

#define FDIM 64

typedef unsigned short u16;
typedef unsigned int u32;
typedef float v2f __attribute__((ext_vector_type(2)));

// pack 4 f32 -> 4 fp8 e4m3 (OCP on gfx950) in one u32
__device__ __forceinline__ u32 pk_fp8x4(float a, float b, float c, float d) {
    u32 p = __builtin_amdgcn_cvt_pk_fp8_f32(a, b, 0, false);
    p = __builtin_amdgcn_cvt_pk_fp8_f32(c, d, p, true);
    return p;
}

// ========= mm compute phase: t[64 rows] = As @ Ws (fp8 out) =========
// Known-good structure: As f32 in LDS (64x65), Ws f32 in LDS.
// SCALE: multiply output row R by rsqrt(cnt[R]+1) before fp8 pack.

template <bool SCALE>
__device__ __forceinline__ void mm_compute(
    u32* __restrict__ t, const int* __restrict__ cnt, int n, int r0,
    float (*__restrict__ As)[FDIM + 1], const float* __restrict__ Ws)
{
    int tid = threadIdx.x;
    int rq = tid >> 4;   // rows rq*4..+3
    int cq = tid & 15;   // cols cq*4..+3
    float acc[4][4];
    #pragma unroll
    for (int i = 0; i < 4; ++i)
        #pragma unroll
        for (int j = 0; j < 4; ++j) acc[i][j] = 0.f;

    const float4* Ws4 = (const float4*)Ws;
    #pragma unroll 4
    for (int k = 0; k < FDIM; ++k) {
        float4 w = Ws4[k * 16 + cq];
        float a[4];
        #pragma unroll
        for (int i = 0; i < 4; ++i) a[i] = As[rq * 4 + i][k];
        #pragma unroll
        for (int i = 0; i < 4; ++i) {
            acc[i][0] = fmaf(a[i], w.x, acc[i][0]);
            acc[i][1] = fmaf(a[i], w.y, acc[i][1]);
            acc[i][2] = fmaf(a[i], w.z, acc[i][2]);
            acc[i][3] = fmaf(a[i], w.w, acc[i][3]);
        }
    }

    #pragma unroll
    for (int i = 0; i < 4; ++i) {
        int R = r0 + rq * 4 + i;
        if (R < n) {
            float sc = 1.0f;
            if (SCALE) sc = rsqrtf((float)cnt[R] + 1.0f);
            t[(size_t)R * 16 + cq] =
                pk_fp8x4(acc[i][0] * sc, acc[i][1] * sc,
                         acc[i][2] * sc, acc[i][3] * sc);
        }
    }
}

// ===== combined dispatch: CSR-fill blocks (first) + matmul1 blocks =========
// Fill: partitioned grid-stride, 8 independent atomic chains in flight.
// (Proven insensitive to wave count / depth / counter padding.)

__global__ __launch_bounds__(256) void k_mm_fill(
    const float* __restrict__ x, const float* __restrict__ W1,
    u32* __restrict__ t,
    const int* __restrict__ src, const int* __restrict__ dst,
    int* __restrict__ cnt, int* __restrict__ csr,
    int n, int E, int cap, int fill_blocks)
{
    __shared__ float As[64][FDIM + 1];
    __shared__ float Ws[FDIM * FDIM];

    if ((int)blockIdx.x < fill_blocks) {
        int stride = fill_blocks * 256;
        int e = blockIdx.x * 256 + threadIdx.x;
        for (; e + 7 * stride < E; e += 8 * stride) {
            int d[8], s[8], p[8];
            #pragma unroll
            for (int u = 0; u < 8; ++u)
                d[u] = __builtin_nontemporal_load(&dst[e + u * stride]);
            #pragma unroll
            for (int u = 0; u < 8; ++u)
                s[u] = __builtin_nontemporal_load(&src[e + u * stride]);
            #pragma unroll
            for (int u = 0; u < 8; ++u) p[u] = atomicAdd(&cnt[d[u]], 1);
            #pragma unroll
            for (int u = 0; u < 8; ++u)
                if (p[u] < cap) csr[(size_t)d[u] * cap + p[u]] = s[u];
        }
        for (; e < E; e += stride) {
            int d = dst[e];
            int p = atomicAdd(&cnt[d], 1);
            if (p < cap) csr[(size_t)d * cap + p] = src[e];
        }
        return;
    }

    int blk = blockIdx.x - fill_blocks;
    int r0 = blk * 64;
    int tid = threadIdx.x;
    #pragma unroll
    for (int i = 0; i < 4; ++i)
        ((float4*)Ws)[tid + 256 * i] = ((const float4*)W1)[tid + 256 * i];

    // stage x rows (f32, no bias, no relu)
    #pragma unroll
    for (int i = 0; i < 4; ++i) {
        int idx = tid + 256 * i;
        int r = idx >> 4;
        int kq = idx & 15;
        float4 v = make_float4(0.f, 0.f, 0.f, 0.f);
        int R = r0 + r;
        if (R < n) v = ((const float4*)x)[(size_t)R * 16 + kq];
        As[r][kq * 4 + 0] = v.x;
        As[r][kq * 4 + 1] = v.y;
        As[r][kq * 4 + 2] = v.z;
        As[r][kq * 4 + 3] = v.w;
    }
    __syncthreads();
    mm_compute<false>(t, nullptr, n, r0, As, Ws);
}

// ======= gather-aggregate body for one node (16-lane group) ================
// KNOWN-GOOD pattern restored: single fully-UNCONDITIONAL 16-deep gather
// batch per csr chunk. Invalid lanes use sv = -1 -> gather hits the 64B
// zero row placed immediately before each t buffer (cache-hot, decodes to
// 0.0). One vmcnt wait per chunk; full memory-level parallelism.
// SCALED=true: t rows already carry dinv_j -> just sum.
// SCALED=false (layer 1): gather cnt[sv] + rsqrt in chain, times dj.

template <bool SCALED>
__device__ __forceinline__ float4 agg_node(
    int i, const int* __restrict__ cnt, const int* __restrict__ csr,
    const u32* __restrict__ t, int cap, int li, int nbase)
{
    int dg = cnt[i];
    float di = rsqrtf((float)dg + 1.0f);
    int m = dg < cap ? dg : cap;

    u32 sp = t[(size_t)i * 16 + li];
    v2f s0 = __builtin_amdgcn_cvt_pk_f32_fp8(sp, false);
    v2f s1 = __builtin_amdgcn_cvt_pk_f32_fp8(sp, true);
    float4 A0, A1, A2, A3;
    if (SCALED) {
        A0 = make_float4(s0.x, s0.y, s1.x, s1.y);
    } else {
        A0 = make_float4(s0.x * di, s0.y * di, s1.x * di, s1.y * di);
    }
    A1 = make_float4(0.f, 0.f, 0.f, 0.f);
    A2 = make_float4(0.f, 0.f, 0.f, 0.f);
    A3 = make_float4(0.f, 0.f, 0.f, 0.f);

    const int* row = csr + (size_t)i * cap;

    for (int c0 = 0; c0 < m; c0 += 16) {
        int cm = m - c0; if (cm > 16) cm = 16;
        int sv = -1; float dvv = 0.f;
        if (li < cm) {
            sv = __builtin_nontemporal_load(&row[c0 + li]);
            if (!SCALED) dvv = rsqrtf((float)cnt[sv] + 1.0f);
        }
        int jv[16]; float dj[16]; u32 v[16];
        #pragma unroll
        for (int u = 0; u < 16; ++u) {
            jv[u] = __shfl(sv, nbase + u);
            if (!SCALED) dj[u] = __shfl(dvv, nbase + u);
        }
        #pragma unroll
        for (int u = 0; u < 16; ++u)
            v[u] = t[(long long)jv[u] * 16 + li];   // jv=-1 -> zero row
        #pragma unroll
        for (int u = 0; u < 16; ++u) {
            v2f x0 = __builtin_amdgcn_cvt_pk_f32_fp8(v[u], false);
            v2f x1 = __builtin_amdgcn_cvt_pk_f32_fp8(v[u], true);
            float4* Ap = (u & 3) == 0 ? &A0 : (u & 3) == 1 ? &A1 :
                         (u & 3) == 2 ? &A2 : &A3;
            if (SCALED) {
                Ap->x += x0.x; Ap->y += x0.y;
                Ap->z += x1.x; Ap->w += x1.y;
            } else {
                Ap->x = fmaf(x0.x, dj[u], Ap->x);
                Ap->y = fmaf(x0.y, dj[u], Ap->y);
                Ap->z = fmaf(x1.x, dj[u], Ap->z);
                Ap->w = fmaf(x1.y, dj[u], Ap->w);
            }
        }
    }

    float4 O;
    O.x = ((A0.x + A1.x) + (A2.x + A3.x)) * di;
    O.y = ((A0.y + A1.y) + (A2.y + A3.y)) * di;
    O.z = ((A0.z + A1.z) + (A2.z + A3.z)) * di;
    O.w = ((A0.w + A1.w) + (A2.w + A3.w)) * di;
    return O;
}

// == fused aggregate + matmul: block aggregates 64 nodes into As (f32 LDS,
// no bf16 round-trip), then runs the mm compute phase. ==

template <bool SCALED_IN>
__global__ __launch_bounds__(256) void k_aggmm(
    const int* __restrict__ cnt, const int* __restrict__ csr,
    const u32* __restrict__ tin, const float* __restrict__ Wm,
    const float* __restrict__ bias, u32* __restrict__ tout,
    int n, int cap)
{
    __shared__ float As[64][FDIM + 1];
    __shared__ float Ws[FDIM * FDIM];
    int tid = threadIdx.x;
    #pragma unroll
    for (int i = 0; i < 4; ++i)
        ((float4*)Ws)[tid + 256 * i] = ((const float4*)Wm)[tid + 256 * i];

    int r0 = blockIdx.x * 64;
    int group = tid >> 4;          // 0..15
    int li = tid & 15;
    int nbase = ((tid & 63) >> 4) << 4;
    float4 b = ((const float4*)bias)[li];

    #pragma unroll 1
    for (int r = 0; r < 4; ++r) {
        int row = r * 16 + group;
        int i = r0 + row;
        float4 v = make_float4(0.f, 0.f, 0.f, 0.f);
        if (i < n) {
            float4 O = agg_node<SCALED_IN>(i, cnt, csr, tin, cap, li, nbase);
            v.x = fmaxf(O.x + b.x, 0.f);
            v.y = fmaxf(O.y + b.y, 0.f);
            v.z = fmaxf(O.z + b.z, 0.f);
            v.w = fmaxf(O.w + b.w, 0.f);
        }
        As[row][li * 4 + 0] = v.x;
        As[row][li * 4 + 1] = v.y;
        As[row][li * 4 + 2] = v.z;
        As[row][li * 4 + 3] = v.w;
    }
    __syncthreads();
    mm_compute<true>(tout, cnt, n, r0, As, Ws);
}

// == layer-3 aggregate fused with pool AND the final reduce+linear ==

__global__ __launch_bounds__(256) void k_agg_pool(
    const int* __restrict__ cnt, const int* __restrict__ csr,
    const u32* __restrict__ t, const int* __restrict__ batch,
    float* __restrict__ partial, int* __restrict__ done,
    const float* __restrict__ b3, const float* __restrict__ Wlin,
    const float* __restrict__ blin, float* __restrict__ out,
    int n, int cap, int npart, int fout)
{
    int g = blockIdx.x / npart;
    int part = blockIdx.x - g * npart;
    int tid = threadIdx.x;

    int lo = 0, hi = n;
    while (lo < hi) { int mid = (lo + hi) >> 1; if (batch[mid] < g) lo = mid + 1; else hi = mid; }
    int start = lo;
    hi = n;
    while (lo < hi) { int mid = (lo + hi) >> 1; if (batch[mid] <= g) lo = mid + 1; else hi = mid; }
    int end = lo;

    int group = tid >> 4;     // 0..15
    int li = tid & 15;
    int nbase = ((tid & 63) >> 4) << 4;

    float4 acc = make_float4(0.f, 0.f, 0.f, 0.f);
    for (int i = start + part * 16 + group; i < end; i += npart * 16) {
        float4 O = agg_node<true>(i, cnt, csr, t, cap, li, nbase);
        acc.x += O.x; acc.y += O.y; acc.z += O.z; acc.w += O.w;
    }

    __shared__ float4 red[16][16];
    red[group][li] = acc;
    __syncthreads();
    if (tid < 16) {
        float4 s = make_float4(0.f, 0.f, 0.f, 0.f);
        #pragma unroll
        for (int q = 0; q < 16; ++q) {
            s.x += red[q][tid].x; s.y += red[q][tid].y;
            s.z += red[q][tid].z; s.w += red[q][tid].w;
        }
        ((float4*)partial)[((size_t)g * npart + part) * 16 + tid] = s;
    }

    // ---- last block per graph reduces + final linear ----
    __threadfence();
    __syncthreads();
    __shared__ int lastflag;
    if (tid == 0) {
        int old = atomicAdd(&done[g], 1);
        lastflag = (old == npart - 1);
    }
    __syncthreads();
    if (!lastflag) return;
    __threadfence();   // acquire: other blocks' partials now visible

    int cg = end - start;
    __shared__ float pooled[64];
    if (tid < 64) {
        float v = 0.f;
        for (int p = 0; p < npart; ++p)
            v += partial[((size_t)g * npart + p) * 64 + tid];
        pooled[tid] = (cg > 0) ? (v / (float)cg + b3[tid]) : 0.f;
    }
    __syncthreads();
    if (tid < fout) {
        float o = blin[tid];
        for (int k = 0; k < 64; ++k) o += pooled[k] * Wlin[k * fout + tid];
        out[(size_t)g * fout + tid] = o;
    }
}

// ================= launcher =================

extern "C" void kernel_launch(void* const* d_in, const int* in_sizes, int n_in,
                              void* d_out, int out_size, void* d_ws, size_t ws_size,
                              hipStream_t stream) {
    const float* x     = (const float*)d_in[0];
    const int*   ei    = (const int*)d_in[1];
    const int*   batch = (const int*)d_in[2];
    const float* W1 = (const float*)d_in[3];
    const float* b1 = (const float*)d_in[4];
    const float* W2 = (const float*)d_in[5];
    const float* b2 = (const float*)d_in[6];
    const float* W3 = (const float*)d_in[7];
    const float* b3 = (const float*)d_in[8];
    const float* Wl = (const float*)d_in[9];
    const float* bl = (const float*)d_in[10];

    int n = in_sizes[0] / 64;
    int E = in_sizes[1] / 2;
    int fout = in_sizes[10];
    int ngraphs = out_size / fout;

    const int* srcp = ei;
    const int* dstp = ei + E;

    const int npart = 16;

    // ws layout: cnt | done | zA (zero row) | tA | zB (zero row) | tB |
    //            partial | csr
    // One memset covers cnt..zB (tA inside is overwritten by the fill mm).
    int* cnt = (int*)d_ws;                           // n
    int* done = cnt + n;                             // ngraphs
    u32* zA  = (u32*)(done + ngraphs);               // 16 (zero row for tA)
    u32* tA  = zA + 16;                              // n*16
    u32* zB  = tA + (size_t)n * 16;                  // 16 (zero row for tB)
    u32* tB  = zB + 16;                              // n*16
    float* partial = (float*)(tB + (size_t)n * 16);  // ngraphs*npart*64
    int* csr = (int*)(partial + (size_t)ngraphs * npart * 64);

    size_t fixed = (size_t)n * 4 + (size_t)ngraphs * 4 + 128 +
                   (size_t)n * 128 + (size_t)ngraphs * npart * 64 * 4;
    int cap = 64;
    while (cap > 32 && fixed + (size_t)n * cap * 4 > ws_size) cap -= 8;

    int mm_blocks = (n + 63) / 64;
    int fill_blocks = 256;

    // single memset: cnt + done + zA + tA + zB
    size_t mset = (size_t)(n + ngraphs) * 4 + 64 + (size_t)n * 64 + 64;
    hipMemsetAsync(cnt, 0, mset, stream);
    // CSR build + t1 = x @ W1 (fp8, unscaled), one dispatch
    k_mm_fill<<<fill_blocks + mm_blocks, 256, 0, stream>>>(
        x, W1, tA, srcp, dstp, cnt, csr, n, E, cap, fill_blocks);

    // layer1 agg (unscaled t1) + layer2 matmul -> t2 (pre-scaled)
    k_aggmm<false><<<mm_blocks, 256, 0, stream>>>(cnt, csr, tA, W2, b1, tB, n, cap);
    // layer2 agg (scaled t2) + layer3 matmul -> t3 (pre-scaled)
    k_aggmm<true><<<mm_blocks, 256, 0, stream>>>(cnt, csr, tB, W3, b2, tA, n, cap);
    // layer3 agg + pool + final linear (last-block reduce)
    k_agg_pool<<<ngraphs * npart, 256, 0, stream>>>(
        cnt, csr, tA, batch, partial, done, b3, Wl, bl,
        (float*)d_out, n, cap, npart, fout);
}

// Round 5
// 252.990 us; speedup vs baseline: 1.4009x; 1.3471x over previous
//
#include <hip/hip_runtime.h>

#define FDIM 64

typedef unsigned short u16;
typedef unsigned int u32;
typedef float v2f __attribute__((ext_vector_type(2)));

// pack 4 f32 -> 4 fp8 e4m3 (OCP on gfx950) in one u32
__device__ __forceinline__ u32 pk_fp8x4(float a, float b, float c, float d) {
    u32 p = __builtin_amdgcn_cvt_pk_fp8_f32(a, b, 0, false);
    p = __builtin_amdgcn_cvt_pk_fp8_f32(c, d, p, true);
    return p;
}

// ========= mm compute phase: t[64 rows] = As @ Ws (fp8 out) =========
// Known-good structure: As f32 in LDS (64x65), Ws f32 in LDS.
// SCALE: multiply output row R by rsqrt(cnt[R]+1) before fp8 pack.

template <bool SCALE>
__device__ __forceinline__ void mm_compute(
    u32* __restrict__ t, const int* __restrict__ cnt, int n, int r0,
    float (*__restrict__ As)[FDIM + 1], const float* __restrict__ Ws)
{
    int tid = threadIdx.x;
    int rq = tid >> 4;   // rows rq*4..+3
    int cq = tid & 15;   // cols cq*4..+3
    float acc[4][4];
    #pragma unroll
    for (int i = 0; i < 4; ++i)
        #pragma unroll
        for (int j = 0; j < 4; ++j) acc[i][j] = 0.f;

    const float4* Ws4 = (const float4*)Ws;
    #pragma unroll 4
    for (int k = 0; k < FDIM; ++k) {
        float4 w = Ws4[k * 16 + cq];
        float a[4];
        #pragma unroll
        for (int i = 0; i < 4; ++i) a[i] = As[rq * 4 + i][k];
        #pragma unroll
        for (int i = 0; i < 4; ++i) {
            acc[i][0] = fmaf(a[i], w.x, acc[i][0]);
            acc[i][1] = fmaf(a[i], w.y, acc[i][1]);
            acc[i][2] = fmaf(a[i], w.z, acc[i][2]);
            acc[i][3] = fmaf(a[i], w.w, acc[i][3]);
        }
    }

    #pragma unroll
    for (int i = 0; i < 4; ++i) {
        int R = r0 + rq * 4 + i;
        if (R < n) {
            float sc = 1.0f;
            if (SCALE) sc = rsqrtf((float)cnt[R] + 1.0f);
            t[(size_t)R * 16 + cq] =
                pk_fp8x4(acc[i][0] * sc, acc[i][1] * sc,
                         acc[i][2] * sc, acc[i][3] * sc);
        }
    }
}

// ===== combined dispatch: CSR-fill blocks (first) + matmul1 blocks =========
// Fill: partitioned grid-stride, 8 independent atomic chains in flight.
// (Proven insensitive to wave count / depth / counter padding.)

__global__ __launch_bounds__(256) void k_mm_fill(
    const float* __restrict__ x, const float* __restrict__ W1,
    u32* __restrict__ t,
    const int* __restrict__ src, const int* __restrict__ dst,
    int* __restrict__ cnt, int* __restrict__ csr,
    int n, int E, int cap, int fill_blocks)
{
    __shared__ float As[64][FDIM + 1];
    __shared__ float Ws[FDIM * FDIM];

    if ((int)blockIdx.x < fill_blocks) {
        int stride = fill_blocks * 256;
        int e = blockIdx.x * 256 + threadIdx.x;
        for (; e + 7 * stride < E; e += 8 * stride) {
            int d[8], s[8], p[8];
            #pragma unroll
            for (int u = 0; u < 8; ++u)
                d[u] = __builtin_nontemporal_load(&dst[e + u * stride]);
            #pragma unroll
            for (int u = 0; u < 8; ++u)
                s[u] = __builtin_nontemporal_load(&src[e + u * stride]);
            #pragma unroll
            for (int u = 0; u < 8; ++u) p[u] = atomicAdd(&cnt[d[u]], 1);
            #pragma unroll
            for (int u = 0; u < 8; ++u)
                if (p[u] < cap) csr[(size_t)d[u] * cap + p[u]] = s[u];
        }
        for (; e < E; e += stride) {
            int d = dst[e];
            int p = atomicAdd(&cnt[d], 1);
            if (p < cap) csr[(size_t)d * cap + p] = src[e];
        }
        return;
    }

    int blk = blockIdx.x - fill_blocks;
    int r0 = blk * 64;
    int tid = threadIdx.x;
    #pragma unroll
    for (int i = 0; i < 4; ++i)
        ((float4*)Ws)[tid + 256 * i] = ((const float4*)W1)[tid + 256 * i];

    // stage x rows (f32, no bias, no relu)
    #pragma unroll
    for (int i = 0; i < 4; ++i) {
        int idx = tid + 256 * i;
        int r = idx >> 4;
        int kq = idx & 15;
        float4 v = make_float4(0.f, 0.f, 0.f, 0.f);
        int R = r0 + r;
        if (R < n) v = ((const float4*)x)[(size_t)R * 16 + kq];
        As[r][kq * 4 + 0] = v.x;
        As[r][kq * 4 + 1] = v.y;
        As[r][kq * 4 + 2] = v.z;
        As[r][kq * 4 + 3] = v.w;
    }
    __syncthreads();
    mm_compute<false>(t, nullptr, n, r0, As, Ws);
}

// ======= gather-aggregate body for one node (16-lane group) ================
// Known-good pattern: single fully-UNCONDITIONAL 16-deep gather batch per
// csr chunk. Invalid lanes use sv = -1 -> gather hits the 64B zero row
// placed immediately before each t buffer (cache-hot, decodes to 0.0).
// One vmcnt wait per chunk; full memory-level parallelism.

template <bool SCALED>
__device__ __forceinline__ float4 agg_node(
    int i, const int* __restrict__ cnt, const int* __restrict__ csr,
    const u32* __restrict__ t, int cap, int li, int nbase)
{
    int dg = cnt[i];
    float di = rsqrtf((float)dg + 1.0f);
    int m = dg < cap ? dg : cap;

    u32 sp = t[(size_t)i * 16 + li];
    v2f s0 = __builtin_amdgcn_cvt_pk_f32_fp8(sp, false);
    v2f s1 = __builtin_amdgcn_cvt_pk_f32_fp8(sp, true);
    float4 A0, A1, A2, A3;
    if (SCALED) {
        A0 = make_float4(s0.x, s0.y, s1.x, s1.y);
    } else {
        A0 = make_float4(s0.x * di, s0.y * di, s1.x * di, s1.y * di);
    }
    A1 = make_float4(0.f, 0.f, 0.f, 0.f);
    A2 = make_float4(0.f, 0.f, 0.f, 0.f);
    A3 = make_float4(0.f, 0.f, 0.f, 0.f);

    const int* row = csr + (size_t)i * cap;

    for (int c0 = 0; c0 < m; c0 += 16) {
        int cm = m - c0; if (cm > 16) cm = 16;
        int sv = -1; float dvv = 0.f;
        if (li < cm) {
            sv = __builtin_nontemporal_load(&row[c0 + li]);
            if (!SCALED) dvv = rsqrtf((float)cnt[sv] + 1.0f);
        }
        int jv[16]; float dj[16]; u32 v[16];
        #pragma unroll
        for (int u = 0; u < 16; ++u) {
            jv[u] = __shfl(sv, nbase + u);
            if (!SCALED) dj[u] = __shfl(dvv, nbase + u);
        }
        #pragma unroll
        for (int u = 0; u < 16; ++u)
            v[u] = t[(long long)jv[u] * 16 + li];   // jv=-1 -> zero row
        #pragma unroll
        for (int u = 0; u < 16; ++u) {
            v2f x0 = __builtin_amdgcn_cvt_pk_f32_fp8(v[u], false);
            v2f x1 = __builtin_amdgcn_cvt_pk_f32_fp8(v[u], true);
            float4* Ap = (u & 3) == 0 ? &A0 : (u & 3) == 1 ? &A1 :
                         (u & 3) == 2 ? &A2 : &A3;
            if (SCALED) {
                Ap->x += x0.x; Ap->y += x0.y;
                Ap->z += x1.x; Ap->w += x1.y;
            } else {
                Ap->x = fmaf(x0.x, dj[u], Ap->x);
                Ap->y = fmaf(x0.y, dj[u], Ap->y);
                Ap->z = fmaf(x1.x, dj[u], Ap->z);
                Ap->w = fmaf(x1.y, dj[u], Ap->w);
            }
        }
    }

    float4 O;
    O.x = ((A0.x + A1.x) + (A2.x + A3.x)) * di;
    O.y = ((A0.y + A1.y) + (A2.y + A3.y)) * di;
    O.z = ((A0.z + A1.z) + (A2.z + A3.z)) * di;
    O.w = ((A0.w + A1.w) + (A2.w + A3.w)) * di;
    return O;
}

// == fused aggregate + matmul: block aggregates 64 nodes into As (f32 LDS,
// no bf16 round-trip), then runs the mm compute phase. ==

template <bool SCALED_IN>
__global__ __launch_bounds__(256) void k_aggmm(
    const int* __restrict__ cnt, const int* __restrict__ csr,
    const u32* __restrict__ tin, const float* __restrict__ Wm,
    const float* __restrict__ bias, u32* __restrict__ tout,
    int n, int cap)
{
    __shared__ float As[64][FDIM + 1];
    __shared__ float Ws[FDIM * FDIM];
    int tid = threadIdx.x;
    #pragma unroll
    for (int i = 0; i < 4; ++i)
        ((float4*)Ws)[tid + 256 * i] = ((const float4*)Wm)[tid + 256 * i];

    int r0 = blockIdx.x * 64;
    int group = tid >> 4;          // 0..15
    int li = tid & 15;
    int nbase = ((tid & 63) >> 4) << 4;
    float4 b = ((const float4*)bias)[li];

    #pragma unroll 1
    for (int r = 0; r < 4; ++r) {
        int row = r * 16 + group;
        int i = r0 + row;
        float4 v = make_float4(0.f, 0.f, 0.f, 0.f);
        if (i < n) {
            float4 O = agg_node<SCALED_IN>(i, cnt, csr, tin, cap, li, nbase);
            v.x = fmaxf(O.x + b.x, 0.f);
            v.y = fmaxf(O.y + b.y, 0.f);
            v.z = fmaxf(O.z + b.z, 0.f);
            v.w = fmaxf(O.w + b.w, 0.f);
        }
        As[row][li * 4 + 0] = v.x;
        As[row][li * 4 + 1] = v.y;
        As[row][li * 4 + 2] = v.z;
        As[row][li * 4 + 3] = v.w;
    }
    __syncthreads();
    mm_compute<true>(tout, cnt, n, r0, As, Ws);
}

// == layer-3 aggregate fused with pool partial-sum ONLY ==
// NO fences / atomic ticket here: per-block device-scope fences cost ~90us
// in L2 writeback/invalidate on 8 non-coherent XCD L2s (round 3/4 lesson).
// The cross-block reduce happens in a separate tiny dispatch; the dispatch
// boundary provides visibility with ONE flush instead of 1024.

__global__ __launch_bounds__(256) void k_agg_pool(
    const int* __restrict__ cnt, const int* __restrict__ csr,
    const u32* __restrict__ t, const int* __restrict__ batch,
    float* __restrict__ partial, int n, int cap, int npart)
{
    int g = blockIdx.x / npart;
    int part = blockIdx.x - g * npart;
    int tid = threadIdx.x;

    int lo = 0, hi = n;
    while (lo < hi) { int mid = (lo + hi) >> 1; if (batch[mid] < g) lo = mid + 1; else hi = mid; }
    int start = lo;
    hi = n;
    while (lo < hi) { int mid = (lo + hi) >> 1; if (batch[mid] <= g) lo = mid + 1; else hi = mid; }
    int end = lo;

    int group = tid >> 4;     // 0..15
    int li = tid & 15;
    int nbase = ((tid & 63) >> 4) << 4;

    float4 acc = make_float4(0.f, 0.f, 0.f, 0.f);
    for (int i = start + part * 16 + group; i < end; i += npart * 16) {
        float4 O = agg_node<true>(i, cnt, csr, t, cap, li, nbase);
        acc.x += O.x; acc.y += O.y; acc.z += O.z; acc.w += O.w;
    }

    __shared__ float4 red[16][16];
    red[group][li] = acc;
    __syncthreads();
    if (tid < 16) {
        float4 s = make_float4(0.f, 0.f, 0.f, 0.f);
        #pragma unroll
        for (int q = 0; q < 16; ++q) {
            s.x += red[q][tid].x; s.y += red[q][tid].y;
            s.z += red[q][tid].z; s.w += red[q][tid].w;
        }
        ((float4*)partial)[((size_t)g * npart + part) * 16 + tid] = s;
    }
}

// == final: reduce partials + mean + b3 + Wlin + blin, one block/graph ==

__global__ __launch_bounds__(64) void k_pool2(
    const float* __restrict__ partial, const int* __restrict__ batch,
    const float* __restrict__ b3, const float* __restrict__ Wlin,
    const float* __restrict__ blin, float* __restrict__ out,
    int n, int fout, int npart)
{
    int g = blockIdx.x;
    int tid = threadIdx.x;

    int lo = 0, hi = n;
    while (lo < hi) { int mid = (lo + hi) >> 1; if (batch[mid] < g) lo = mid + 1; else hi = mid; }
    int start = lo;
    hi = n;
    while (lo < hi) { int mid = (lo + hi) >> 1; if (batch[mid] <= g) lo = mid + 1; else hi = mid; }
    int cg = lo - start;

    __shared__ float pooled[64];
    float v = 0.f;
    for (int p = 0; p < npart; ++p)
        v += partial[((size_t)g * npart + p) * 64 + tid];
    pooled[tid] = (cg > 0) ? (v / (float)cg + b3[tid]) : 0.f;
    __syncthreads();
    if (tid < fout) {
        float o = blin[tid];
        for (int k = 0; k < 64; ++k) o += pooled[k] * Wlin[k * fout + tid];
        out[(size_t)g * fout + tid] = o;
    }
}

// ================= launcher =================

extern "C" void kernel_launch(void* const* d_in, const int* in_sizes, int n_in,
                              void* d_out, int out_size, void* d_ws, size_t ws_size,
                              hipStream_t stream) {
    const float* x     = (const float*)d_in[0];
    const int*   ei    = (const int*)d_in[1];
    const int*   batch = (const int*)d_in[2];
    const float* W1 = (const float*)d_in[3];
    const float* b1 = (const float*)d_in[4];
    const float* W2 = (const float*)d_in[5];
    const float* b2 = (const float*)d_in[6];
    const float* W3 = (const float*)d_in[7];
    const float* b3 = (const float*)d_in[8];
    const float* Wl = (const float*)d_in[9];
    const float* bl = (const float*)d_in[10];

    int n = in_sizes[0] / 64;
    int E = in_sizes[1] / 2;
    int fout = in_sizes[10];
    int ngraphs = out_size / fout;

    const int* srcp = ei;
    const int* dstp = ei + E;

    const int npart = 16;

    // ws layout: cnt | zA (zero row) | tA | zB (zero row) | tB | partial | csr
    // One memset covers cnt..zB (tA inside is fully overwritten by the mm).
    int* cnt = (int*)d_ws;                           // n
    u32* zA  = (u32*)(cnt + n);                      // 16 (zero row for tA)
    u32* tA  = zA + 16;                              // n*16
    u32* zB  = tA + (size_t)n * 16;                  // 16 (zero row for tB)
    u32* tB  = zB + 16;                              // n*16
    float* partial = (float*)(tB + (size_t)n * 16);  // ngraphs*npart*64
    int* csr = (int*)(partial + (size_t)ngraphs * npart * 64);

    size_t fixed = (size_t)n * 4 + 128 + (size_t)n * 128 +
                   (size_t)ngraphs * npart * 64 * 4;
    int cap = 64;
    while (cap > 32 && fixed + (size_t)n * cap * 4 > ws_size) cap -= 8;

    int mm_blocks = (n + 63) / 64;
    int fill_blocks = 256;

    // single memset: cnt + zA + tA + zB
    size_t mset = (size_t)n * 4 + 64 + (size_t)n * 64 + 64;
    hipMemsetAsync(cnt, 0, mset, stream);
    // CSR build + t1 = x @ W1 (fp8, unscaled), one dispatch
    k_mm_fill<<<fill_blocks + mm_blocks, 256, 0, stream>>>(
        x, W1, tA, srcp, dstp, cnt, csr, n, E, cap, fill_blocks);

    // layer1 agg (unscaled t1) + layer2 matmul -> t2 (pre-scaled)
    k_aggmm<false><<<mm_blocks, 256, 0, stream>>>(cnt, csr, tA, W2, b1, tB, n, cap);
    // layer2 agg (scaled t2) + layer3 matmul -> t3 (pre-scaled)
    k_aggmm<true><<<mm_blocks, 256, 0, stream>>>(cnt, csr, tB, W3, b2, tA, n, cap);
    // layer3 agg + pool partial-sum (no fences)
    k_agg_pool<<<ngraphs * npart, 256, 0, stream>>>(
        cnt, csr, tA, batch, partial, n, cap, npart);
    // final reduce + linear
    k_pool2<<<ngraphs, 64, 0, stream>>>(partial, batch, b3, Wl, bl,
                                        (float*)d_out, n, fout, npart);
}